// Round 5
// baseline (993.311 us; speedup 1.0000x reference)
//
#include <hip/hip_runtime.h>
#include <math.h>

// Problem constants
#define NB 32          // batch
#define NC 1024        // channels
#define LTOT 680       // total tokens per batch

typedef unsigned short u16;
typedef __bf16 bf16x8 __attribute__((ext_vector_type(8)));
typedef float floatx4 __attribute__((ext_vector_type(4)));

__device__ __forceinline__ u16 f2bf(float f)
{
    union { float f; unsigned u; } v; v.f = f;
    unsigned u = v.u;
    u += 0x7FFFu + ((u >> 16) & 1u);   // RNE
    return (u16)(u >> 16);
}

__device__ __forceinline__ float bf2f(unsigned u)
{
    union { unsigned u; float f; } v; v.u = u << 16; return v.f;
}

// ---------------------------------------------------------------------------
// Async global->LDS 16B copy. LDS dest is wave-uniform base + lane*16 (HW
// semantics); global src is per-lane.
// ---------------------------------------------------------------------------
__device__ __forceinline__ void gload16(const u16* g, u16* l)
{
    typedef __attribute__((address_space(1))) const void gv_t;
    typedef __attribute__((address_space(3))) void lv_t;
    __builtin_amdgcn_global_load_lds(
        (gv_t*)(unsigned long long)(const void*)g,
        (lv_t*)(unsigned int)(unsigned long long)(void*)l,
        16, 0, 0);
}

// 128-tile slot decode (BK=64): slot s in [0,1024) -> (row in [0,128), cq in [0,8))
__device__ __forceinline__ void slot_decode(int s, int* prow, int* pcq)
{
    *prow = ((s >> 7) << 4) | (s & 15);
    *pcq  = (((s >> 6) & 1) << 2) | ((s >> 4) & 3);
}

// 256-tile slot decode (BK=32): slot s in [0,1024) -> (row in [0,256), cq in [0,4))
// Forward: slot = (row>>4)*64 + cq*16 + (row&15)
__device__ __forceinline__ void slot_decode256(int s, int* prow, int* pcq)
{
    *prow = ((s >> 6) << 4) | (s & 15);
    *pcq  = (s >> 4) & 3;
}

// Pipeline fences: counted wait keeps next-tile loads in flight across the
// barrier; raw s_barrier avoids __syncthreads' vmcnt(0) drain.
#define WAIT_VM8()  asm volatile("s_waitcnt vmcnt(8)" ::: "memory")
#define WAIT_VM4()  asm volatile("s_waitcnt vmcnt(4)" ::: "memory")
#define WAIT_VM0()  asm volatile("s_waitcnt vmcnt(0)" ::: "memory")
#define BAR()       __builtin_amdgcn_s_barrier()
#define SCHEDB()    __builtin_amdgcn_sched_barrier(0)

// ===========================================================================
// 256x256-tile bf16 MFMA GEMM, BK=32, 512 threads = 8 waves (2m x 4n grid),
// per-wave output 128x64 (acc[8][4]).  Double-buffered LDS (64KB total ->
// 2 blocks/CU), global_load_lds staging (4 loads/thread/tile), counted
// vmcnt(4) 2-phase pipeline.  OUTBF=1: C stored bf16.  K multiple of 32.
// ===========================================================================
template<int OUTBF>
__global__ __launch_bounds__(512) void gemm256(
    const u16* __restrict__ A, const u16* __restrict__ BT,
    float* __restrict__ C, int M, int N, int K, int lda,
    const float* __restrict__ bias, const float* __restrict__ scale_logit)
{
    __shared__ __align__(16) u16 As[2][8192];   // 16KB per buffer
    __shared__ __align__(16) u16 Bs[2][8192];

    const int tid  = threadIdx.x;
    const int m0   = blockIdx.y << 8;
    const int n0   = blockIdx.x << 8;
    const int wave = tid >> 6;
    const int lane = tid & 63;
    const int mh   = wave & 1;      // m half (128 rows)
    const int nh   = wave >> 1;     // n quarter (64 cols)
    const int lbase = (wave << 6) * 8;   // u16 offset of wave's p=0 slot run

    const u16* aSrc[2];
    const u16* bSrc[2];
#pragma unroll
    for (int p = 0; p < 2; ++p) {
        int s = tid + (p << 9), row, cq;
        slot_decode256(s, &row, &cq);
        int gr = m0 + row; if (gr > M - 1) gr = M - 1;
        aSrc[p] = A + (size_t)gr * lda + (cq << 3);
        int gn = n0 + row; if (gn > N - 1) gn = N - 1;
        bSrc[p] = BT + (size_t)gn * K + (cq << 3);
    }

    floatx4 acc[8][4];
#pragma unroll
    for (int i = 0; i < 8; ++i)
#pragma unroll
        for (int j = 0; j < 4; ++j) acc[i][j] = (floatx4){0.f, 0.f, 0.f, 0.f};

    // prologue: tile 0 -> buf 0
#pragma unroll
    for (int p = 0; p < 2; ++p) gload16(aSrc[p], &As[0][lbase + (p << 12)]);
#pragma unroll
    for (int p = 0; p < 2; ++p) gload16(bSrc[p], &Bs[0][lbase + (p << 12)]);

    const int nt = K >> 5;
    for (int t = 0; t < nt; ++t) {
        const int cur = t & 1;
        if (t + 1 < nt) {
            const int kk = (t + 1) << 5;
#pragma unroll
            for (int p = 0; p < 2; ++p) gload16(aSrc[p] + kk, &As[cur ^ 1][lbase + (p << 12)]);
#pragma unroll
            for (int p = 0; p < 2; ++p) gload16(bSrc[p] + kk, &Bs[cur ^ 1][lbase + (p << 12)]);
            WAIT_VM4();
        } else {
            WAIT_VM0();
        }
        BAR(); SCHEDB();
        {
            bf16x8 a[8], b[4];
#pragma unroll
            for (int i = 0; i < 8; ++i)
                a[i] = *(const bf16x8*)&As[cur][((((mh << 3) + i) << 6) + lane) * 8];
#pragma unroll
            for (int j = 0; j < 4; ++j)
                b[j] = *(const bf16x8*)&Bs[cur][((((nh << 2) + j) << 6) + lane) * 8];
#pragma unroll
            for (int i = 0; i < 8; ++i)
#pragma unroll
                for (int j = 0; j < 4; ++j)
                    acc[i][j] = __builtin_amdgcn_mfma_f32_16x16x32_bf16(a[i], b[j], acc[i][j], 0, 0, 0);
        }
        SCHEDB(); BAR();
    }

    float scale = 1.f;
    if (scale_logit) scale = 1.f / (1.f + __expf(-scale_logit[0]));
    const int col = lane & 15, rquad = lane >> 4;
#pragma unroll
    for (int i = 0; i < 8; ++i) {
#pragma unroll
        for (int j = 0; j < 4; ++j) {
#pragma unroll
            for (int r = 0; r < 4; ++r) {
                int gr = m0 + (mh << 7) + (i << 4) + (rquad << 2) + r;
                int gc = n0 + (nh << 6) + (j << 4) + col;
                if (gr < M && gc < N) {
                    float bb = bias ? bias[gc] : 0.f;
                    float val = scale * (acc[i][j][r] + bb);
                    if (OUTBF) ((u16*)C)[(size_t)gr * N + gc] = f2bf(val);
                    else       C[(size_t)gr * N + gc] = val;
                }
            }
        }
    }
}

// ---------------------------------------------------------------------------
// Batched logits GEMM (256-tile): out[b][680][640] = Q_b @ [sk ; kc_b]^T.
// grid (3n, 3m, 32b); n/m padded to 768 with clamped loads / guarded stores.
// ---------------------------------------------------------------------------
__global__ __launch_bounds__(512) void gemm256_logits(
    const u16* __restrict__ Q, const u16* __restrict__ skb,
    const u16* __restrict__ kcb, float* __restrict__ out)
{
    __shared__ __align__(16) u16 As[2][8192];
    __shared__ __align__(16) u16 Bs[2][8192];

    const int tid  = threadIdx.x;
    const int m0   = blockIdx.y << 8;
    const int n0   = blockIdx.x << 8;
    const int b    = blockIdx.z;
    const int wave = tid >> 6;
    const int lane = tid & 63;
    const int mh   = wave & 1;
    const int nh   = wave >> 1;
    const int lbase = (wave << 6) * 8;

    const u16* Ab = Q   + (size_t)b * 680 * 1024;
    const u16* KC = kcb + (size_t)b * 320 * 1024;

    const u16* aSrc[2];
    const u16* bSrc[2];
#pragma unroll
    for (int p = 0; p < 2; ++p) {
        int s = tid + (p << 9), row, cq;
        slot_decode256(s, &row, &cq);
        int gr = m0 + row; if (gr > 679) gr = 679;
        aSrc[p] = Ab + (size_t)gr * 1024 + (cq << 3);
        int gn = n0 + row; if (gn > 639) gn = 639;
        bSrc[p] = ((gn < 320) ? (skb + (size_t)gn * 1024)
                              : (KC + (size_t)(gn - 320) * 1024)) + (cq << 3);
    }

    floatx4 acc[8][4];
#pragma unroll
    for (int i = 0; i < 8; ++i)
#pragma unroll
        for (int j = 0; j < 4; ++j) acc[i][j] = (floatx4){0.f, 0.f, 0.f, 0.f};

#pragma unroll
    for (int p = 0; p < 2; ++p) gload16(aSrc[p], &As[0][lbase + (p << 12)]);
#pragma unroll
    for (int p = 0; p < 2; ++p) gload16(bSrc[p], &Bs[0][lbase + (p << 12)]);

    for (int t = 0; t < 32; ++t) {
        const int cur = t & 1;
        if (t < 31) {
            const int kk = (t + 1) << 5;
#pragma unroll
            for (int p = 0; p < 2; ++p) gload16(aSrc[p] + kk, &As[cur ^ 1][lbase + (p << 12)]);
#pragma unroll
            for (int p = 0; p < 2; ++p) gload16(bSrc[p] + kk, &Bs[cur ^ 1][lbase + (p << 12)]);
            WAIT_VM4();
        } else {
            WAIT_VM0();
        }
        BAR(); SCHEDB();
        {
            bf16x8 a[8], bb[4];
#pragma unroll
            for (int i = 0; i < 8; ++i)
                a[i] = *(const bf16x8*)&As[cur][((((mh << 3) + i) << 6) + lane) * 8];
#pragma unroll
            for (int j = 0; j < 4; ++j)
                bb[j] = *(const bf16x8*)&Bs[cur][((((nh << 2) + j) << 6) + lane) * 8];
#pragma unroll
            for (int i = 0; i < 8; ++i)
#pragma unroll
                for (int j = 0; j < 4; ++j)
                    acc[i][j] = __builtin_amdgcn_mfma_f32_16x16x32_bf16(a[i], bb[j], acc[i][j], 0, 0, 0);
        }
        SCHEDB(); BAR();
    }

    const int col = lane & 15, rquad = lane >> 4;
#pragma unroll
    for (int i = 0; i < 8; ++i)
#pragma unroll
        for (int j = 0; j < 4; ++j)
#pragma unroll
            for (int r = 0; r < 4; ++r) {
                int gr = m0 + (mh << 7) + (i << 4) + (rquad << 2) + r;
                int gc = n0 + (nh << 6) + (j << 4) + col;
                if (gr < 680 && gc < 640)
                    out[((size_t)b * 680 + gr) * 640 + gc] = acc[i][j][r];
            }
}

// ---------------------------------------------------------------------------
// Batched PV GEMM (256-tile): mem[b][680][1024] bf16 = P_b[680x640] @ [sv;vc_b].
// A = P bf16, row stride 1280 u16.  grid (4n, 3m, 32b).  K=640 -> 20 tiles,
// tiles 0-9 read svT, 10-19 read vcT.
// ---------------------------------------------------------------------------
__global__ __launch_bounds__(512) void gemm256_pv(
    const u16* __restrict__ P, const u16* __restrict__ svT,
    const u16* __restrict__ vcT, u16* __restrict__ out)
{
    __shared__ __align__(16) u16 As[2][8192];
    __shared__ __align__(16) u16 Bs[2][8192];

    const int tid  = threadIdx.x;
    const int m0   = blockIdx.y << 8;
    const int n0   = blockIdx.x << 8;
    const int b    = blockIdx.z;
    const int wave = tid >> 6;
    const int lane = tid & 63;
    const int mh   = wave & 1;
    const int nh   = wave >> 1;
    const int lbase = (wave << 6) * 8;

    const u16* aSrc[2];
    const u16* bSrcS[2];
    const u16* bSrcC[2];
#pragma unroll
    for (int p = 0; p < 2; ++p) {
        int s = tid + (p << 9), row, cq;
        slot_decode256(s, &row, &cq);
        int gr = m0 + row; if (gr > 679) gr = 679;
        aSrc[p] = P + ((size_t)b * 680 + gr) * 1280 + (cq << 3);
        int gn = n0 + row;                    // < 1024 always
        bSrcS[p] = svT + (size_t)gn * 320 + (cq << 3);
        bSrcC[p] = vcT + ((size_t)b * 1024 + gn) * 320 + (cq << 3);
    }

    floatx4 acc[8][4];
#pragma unroll
    for (int i = 0; i < 8; ++i)
#pragma unroll
        for (int j = 0; j < 4; ++j) acc[i][j] = (floatx4){0.f, 0.f, 0.f, 0.f};

#pragma unroll
    for (int p = 0; p < 2; ++p) gload16(aSrc[p], &As[0][lbase + (p << 12)]);
#pragma unroll
    for (int p = 0; p < 2; ++p) gload16(bSrcS[p], &Bs[0][lbase + (p << 12)]);

    for (int t = 0; t < 20; ++t) {
        const int cur = t & 1;
        if (t < 19) {
            const int tn = t + 1;
            const int kk = tn << 5;
#pragma unroll
            for (int p = 0; p < 2; ++p) gload16(aSrc[p] + kk, &As[cur ^ 1][lbase + (p << 12)]);
#pragma unroll
            for (int p = 0; p < 2; ++p) {
                const u16* bp = (tn < 10) ? (bSrcS[p] + kk) : (bSrcC[p] + ((tn - 10) << 5));
                gload16(bp, &Bs[cur ^ 1][lbase + (p << 12)]);
            }
            WAIT_VM4();
        } else {
            WAIT_VM0();
        }
        BAR(); SCHEDB();
        {
            bf16x8 a[8], bb[4];
#pragma unroll
            for (int i = 0; i < 8; ++i)
                a[i] = *(const bf16x8*)&As[cur][((((mh << 3) + i) << 6) + lane) * 8];
#pragma unroll
            for (int j = 0; j < 4; ++j)
                bb[j] = *(const bf16x8*)&Bs[cur][((((nh << 2) + j) << 6) + lane) * 8];
#pragma unroll
            for (int i = 0; i < 8; ++i)
#pragma unroll
                for (int j = 0; j < 4; ++j)
                    acc[i][j] = __builtin_amdgcn_mfma_f32_16x16x32_bf16(a[i], bb[j], acc[i][j], 0, 0, 0);
        }
        SCHEDB(); BAR();
    }

    const int col = lane & 15, rquad = lane >> 4;
#pragma unroll
    for (int i = 0; i < 8; ++i)
#pragma unroll
        for (int j = 0; j < 4; ++j)
#pragma unroll
            for (int r = 0; r < 4; ++r) {
                int gr = m0 + (mh << 7) + (i << 4) + (rquad << 2) + r;
                int gc = n0 + (nh << 6) + (j << 4) + col;
                if (gr < 680)
                    out[((size_t)b * 680 + gr) * 1024 + gc] = f2bf(acc[i][j][r]);
            }
}

// ===========================================================================
// 128x128-tile GEMM (BK=64, 4 waves) — kept for small-N work:
// ceW/seW statics, head stage-1 (N=128).
// ===========================================================================
template<int OUTBF>
__global__ __launch_bounds__(256) void gemm_mfma(
    const u16* __restrict__ A, const u16* __restrict__ BT,
    float* __restrict__ C, int M, int N, int K, int lda,
    const float* __restrict__ bias, const float* __restrict__ scale_logit)
{
    __shared__ __align__(16) u16 As[2][8192];
    __shared__ __align__(16) u16 Bs[2][8192];

    const int tid  = threadIdx.x;
    const int m0   = blockIdx.y << 7;
    const int n0   = blockIdx.x << 7;
    const int wave = tid >> 6;
    const int lane = tid & 63;
    const int mh   = wave & 1;
    const int nh   = wave >> 1;
    const int lbase = (wave << 6) * 8;

    const u16* aSrc[4];
    const u16* bSrc[4];
#pragma unroll
    for (int p = 0; p < 4; ++p) {
        int s = tid + (p << 8), row, cq;
        slot_decode(s, &row, &cq);
        int gr = m0 + row; if (gr > M - 1) gr = M - 1;
        aSrc[p] = A + (size_t)gr * lda + (cq << 3);
        int gn = n0 + row; if (gn > N - 1) gn = N - 1;
        bSrc[p] = BT + (size_t)gn * K + (cq << 3);
    }

    floatx4 acc[4][4];
#pragma unroll
    for (int i = 0; i < 4; ++i)
#pragma unroll
        for (int j = 0; j < 4; ++j) acc[i][j] = (floatx4){0.f, 0.f, 0.f, 0.f};

#pragma unroll
    for (int p = 0; p < 4; ++p) gload16(aSrc[p], &As[0][lbase + (p << 11)]);
#pragma unroll
    for (int p = 0; p < 4; ++p) gload16(bSrc[p], &Bs[0][lbase + (p << 11)]);

    const int nt = K >> 6;
    for (int t = 0; t < nt; ++t) {
        const int cur = t & 1;
        if (t + 1 < nt) {
            const int kk = (t + 1) << 6;
#pragma unroll
            for (int p = 0; p < 4; ++p) gload16(aSrc[p] + kk, &As[cur ^ 1][lbase + (p << 11)]);
#pragma unroll
            for (int p = 0; p < 4; ++p) gload16(bSrc[p] + kk, &Bs[cur ^ 1][lbase + (p << 11)]);
            WAIT_VM8();
        } else {
            WAIT_VM0();
        }
        BAR(); SCHEDB();
#pragma unroll
        for (int kh = 0; kh < 2; ++kh) {
            bf16x8 a[4], b[4];
#pragma unroll
            for (int i = 0; i < 4; ++i)
                a[i] = *(const bf16x8*)&As[cur][(((((mh << 2) + i) << 1) | kh) * 64 + lane) * 8];
#pragma unroll
            for (int j = 0; j < 4; ++j)
                b[j] = *(const bf16x8*)&Bs[cur][(((((nh << 2) + j) << 1) | kh) * 64 + lane) * 8];
#pragma unroll
            for (int i = 0; i < 4; ++i)
#pragma unroll
                for (int j = 0; j < 4; ++j)
                    acc[i][j] = __builtin_amdgcn_mfma_f32_16x16x32_bf16(a[i], b[j], acc[i][j], 0, 0, 0);
        }
        SCHEDB(); BAR();
    }

    float scale = 1.f;
    if (scale_logit) scale = 1.f / (1.f + __expf(-scale_logit[0]));
    const int col = lane & 15, rquad = lane >> 4;
#pragma unroll
    for (int i = 0; i < 4; ++i) {
#pragma unroll
        for (int j = 0; j < 4; ++j) {
#pragma unroll
            for (int r = 0; r < 4; ++r) {
                int gr = m0 + (mh << 6) + (i << 4) + (rquad << 2) + r;
                int gc = n0 + (nh << 6) + (j << 4) + col;
                if (gr < M && gc < N) {
                    float bb = bias ? bias[gc] : 0.f;
                    float val = scale * (acc[i][j][r] + bb);
                    if (OUTBF) ((u16*)C)[(size_t)gr * N + gc] = f2bf(val);
                    else       C[(size_t)gr * N + gc] = val;
                }
            }
        }
    }
}

// ---------------------------------------------------------------------------
// Alpha hidden GEMM (128-tile): h[21760][128] bf16 = gelu( Q @ aW1_topT
//                     + ceW[cid[b]] + seW[isc(l)] )   (seW includes ab1)
// ---------------------------------------------------------------------------
__global__ __launch_bounds__(256) void gemm_halpha(
    const u16* __restrict__ Q, const u16* __restrict__ W,
    const float* __restrict__ ceW, const float* __restrict__ seW,
    const int* __restrict__ cat_ids, u16* __restrict__ h)
{
    __shared__ __align__(16) u16 As[2][8192];
    __shared__ __align__(16) u16 Bs[2][8192];

    const int tid  = threadIdx.x;
    const int m0   = blockIdx.x << 7;
    const int wave = tid >> 6;
    const int lane = tid & 63;
    const int mh   = wave & 1;
    const int nh   = wave >> 1;
    const int lbase = (wave << 6) * 8;

    const u16* aSrc[4];
    const u16* bSrc[4];
#pragma unroll
    for (int p = 0; p < 4; ++p) {
        int s = tid + (p << 8), row, cq;
        slot_decode(s, &row, &cq);
        aSrc[p] = Q + (size_t)(m0 + row) * 1024 + (cq << 3);
        bSrc[p] = W + (size_t)row * 1024 + (cq << 3);
    }

    floatx4 acc[4][4];
#pragma unroll
    for (int i = 0; i < 4; ++i)
#pragma unroll
        for (int j = 0; j < 4; ++j) acc[i][j] = (floatx4){0.f, 0.f, 0.f, 0.f};

#pragma unroll
    for (int p = 0; p < 4; ++p) gload16(aSrc[p], &As[0][lbase + (p << 11)]);
#pragma unroll
    for (int p = 0; p < 4; ++p) gload16(bSrc[p], &Bs[0][lbase + (p << 11)]);

    for (int t = 0; t < 16; ++t) {
        const int cur = t & 1;
        if (t < 15) {
            const int kk = (t + 1) << 6;
#pragma unroll
            for (int p = 0; p < 4; ++p) gload16(aSrc[p] + kk, &As[cur ^ 1][lbase + (p << 11)]);
#pragma unroll
            for (int p = 0; p < 4; ++p) gload16(bSrc[p] + kk, &Bs[cur ^ 1][lbase + (p << 11)]);
            WAIT_VM8();
        } else {
            WAIT_VM0();
        }
        BAR(); SCHEDB();
#pragma unroll
        for (int kh = 0; kh < 2; ++kh) {
            bf16x8 a[4], bb[4];
#pragma unroll
            for (int i = 0; i < 4; ++i)
                a[i] = *(const bf16x8*)&As[cur][(((((mh << 2) + i) << 1) | kh) * 64 + lane) * 8];
#pragma unroll
            for (int j = 0; j < 4; ++j)
                bb[j] = *(const bf16x8*)&Bs[cur][(((((nh << 2) + j) << 1) | kh) * 64 + lane) * 8];
#pragma unroll
            for (int i = 0; i < 4; ++i)
#pragma unroll
                for (int j = 0; j < 4; ++j)
                    acc[i][j] = __builtin_amdgcn_mfma_f32_16x16x32_bf16(a[i], bb[j], acc[i][j], 0, 0, 0);
        }
        SCHEDB(); BAR();
    }

    const int se_[9] = {1,5,14,30,55,91,155,255,424};
    const int col = lane & 15, rquad = lane >> 4;
#pragma unroll
    for (int i = 0; i < 4; ++i) {
#pragma unroll
        for (int r = 0; r < 4; ++r) {
            int gr = m0 + (mh << 6) + (i << 4) + (rquad << 2) + r;
            int b  = gr / 680;
            int l  = gr - b * 680;
            int isc = 0;
#pragma unroll
            for (int k = 0; k < 9; ++k) if (l >= se_[k]) isc = k + 1;
            int cid = cat_ids[b]; if (cid < 0) cid = 0;
            const float* cw = ceW + cid * 128;
            const float* sw = seW + isc * 128;
#pragma unroll
            for (int j = 0; j < 4; ++j) {
                int gc = (nh << 6) + (j << 4) + col;
                float val = acc[i][j][r] + cw[gc] + sw[gc];
                float g = 0.5f * val * (1.0f + erff(val * 0.70710678118654752f));
                h[(size_t)gr * 128 + gc] = f2bf(g);
            }
        }
    }
}

// ---------------------------------------------------------------------------
// alpha[row] = valid ? sigmoid( dot(h[row], aW2) + ab2 ) : 0.
// ---------------------------------------------------------------------------
__global__ __launch_bounds__(256) void alpha_reduce(
    const u16* __restrict__ h, const float* __restrict__ aW2,
    const float* __restrict__ ab2, const int* __restrict__ cat_ids,
    float* __restrict__ alpha)
{
    const int wave = threadIdx.x >> 6;
    const int lane = threadIdx.x & 63;
    const int row  = (blockIdx.x << 2) + wave;   // < 21760 exact

    const unsigned pk = *(const unsigned*)(h + (size_t)row * 128 + (lane << 1));
    float s = bf2f(pk) * aW2[lane << 1] + bf2f(pk >> 16) * aW2[(lane << 1) + 1];
#pragma unroll
    for (int k = 32; k >= 1; k >>= 1) s += __shfl_xor(s, k);
    if (lane == 0) {
        int b = row / 680;
        float al = 0.f;
        if (cat_ids[b] >= 0) al = 1.f / (1.f + expf(-(s + ab2[0])));
        alpha[row] = al;
    }
}

// ---------------------------------------------------------------------------
// Masked dual softmax, one wave per token row; folds alpha into P.
// Reads logits row [640] fp32, writes P row [640] bf16 IN PLACE.
// ---------------------------------------------------------------------------
__global__ __launch_bounds__(256) void softmax_kernel(
    float* __restrict__ logits, const float* __restrict__ alpha,
    const float* __restrict__ log_temp)
{
    const int tid  = threadIdx.x;
    const int w    = tid >> 6;
    const int lane = tid & 63;
    const int b    = blockIdx.y;
    const int l    = (blockIdx.x << 2) + w;     // 680 = 170*4, exact

    const int se[10] = {1,5,14,30,55,91,155,255,424,680};
    int isc = 0;
#pragma unroll
    for (int k = 0; k < 9; ++k) if (l >= se[k]) isc = k + 1;
    const int NK = (isc + 1) << 5;

    float temp = __expf(log_temp[0]);
    temp = fminf(fmaxf(temp, 0.05f), 1.0f);
    const float Ksc = 0.03125f / temp;

    float* row = logits + ((size_t)b * 680 + l) * 640;

    float ls[5], lc[5];
#pragma unroll
    for (int u = 0; u < 5; ++u) {
        int j = lane + (u << 6);
        bool v = j < NK;
        ls[u] = v ? row[j]       : -1e30f;
        lc[u] = v ? row[320 + j] : -1e30f;
    }
    float mxs = -1e30f, mxc = -1e30f;
#pragma unroll
    for (int u = 0; u < 5; ++u) { mxs = fmaxf(mxs, ls[u]); mxc = fmaxf(mxc, lc[u]); }
#pragma unroll
    for (int k = 32; k >= 1; k >>= 1) {
        mxs = fmaxf(mxs, __shfl_xor(mxs, k));
        mxc = fmaxf(mxc, __shfl_xor(mxc, k));
    }
    float es[5], ec[5], ss = 0.f, sc = 0.f;
#pragma unroll
    for (int u = 0; u < 5; ++u) {
        int j = lane + (u << 6);
        bool v = j < NK;
        es[u] = v ? __expf((ls[u] - mxs) * Ksc) : 0.f;
        ec[u] = v ? __expf((lc[u] - mxc) * Ksc) : 0.f;
        ss += es[u]; sc += ec[u];
    }
#pragma unroll
    for (int k = 32; k >= 1; k >>= 1) {
        ss += __shfl_xor(ss, k);
        sc += __shfl_xor(sc, k);
    }
    const float al = alpha[b * LTOT + l];
    const float wS = (1.f - al) / ss;
    const float wC = al / sc;

    u16* po = (u16*)row;
#pragma unroll
    for (int u = 0; u < 5; ++u) {
        int j = lane + (u << 6);
        po[j]       = f2bf(es[u] * wS);
        po[320 + j] = f2bf(ec[u] * wC);
    }
}

// ---------------------------------------------------------------------------
// fp32 elementwise -> bf16 (n4 = element count / 4)
// ---------------------------------------------------------------------------
__global__ __launch_bounds__(256) void castbf(
    const float* __restrict__ in, u16* __restrict__ out, int n4)
{
    int i = blockIdx.x * 256 + threadIdx.x;
    const int stride = gridDim.x * 256;
    for (; i < n4; i += stride) {
        const float4 v = ((const float4*)in)[i];
        uint2 o;
        o.x = (unsigned)f2bf(v.x) | ((unsigned)f2bf(v.y) << 16);
        o.y = (unsigned)f2bf(v.z) | ((unsigned)f2bf(v.w) << 16);
        ((uint2*)out)[i] = o;
    }
}

// ---------------------------------------------------------------------------
// transpose + cast: out[Cc][R] bf16 = in[R][Cc]^T. grid (ceil(Cc/32), ceil(R/32))
// ---------------------------------------------------------------------------
__global__ __launch_bounds__(256) void tcast(
    const float* __restrict__ in, u16* __restrict__ out, int R, int Cc)
{
    __shared__ float t[32][33];
    const int bx = blockIdx.x * 32;   // Cc
    const int by = blockIdx.y * 32;   // R
    const int x = threadIdx.x & 31;
    const int y0 = threadIdx.x >> 5;
#pragma unroll
    for (int yy = y0; yy < 32; yy += 8)
        t[yy][x] = (by + yy < R && bx + x < Cc)
                 ? in[(size_t)(by + yy) * Cc + bx + x] : 0.f;
    __syncthreads();
#pragma unroll
    for (int yy = y0; yy < 32; yy += 8)
        if (bx + yy < Cc && by + x < R)
            out[(size_t)(bx + yy) * R + by + x] = f2bf(t[x][yy]);
}

// ---------------------------------------------------------------------------
// 32x32 fp32 transpose, same grid convention, guarded.
// ---------------------------------------------------------------------------
__global__ __launch_bounds__(256) void transpose32(
    const float* __restrict__ in, float* __restrict__ out, int R, int Cc)
{
    __shared__ float t[32][33];
    const int bx = blockIdx.x * 32;
    const int by = blockIdx.y * 32;
    const int x = threadIdx.x & 31;
    const int y0 = threadIdx.x >> 5;
#pragma unroll
    for (int yy = y0; yy < 32; yy += 8)
        t[yy][x] = (by + yy < R && bx + x < Cc)
                 ? in[(size_t)(by + yy) * Cc + bx + x] : 0.f;
    __syncthreads();
#pragma unroll
    for (int yy = y0; yy < 32; yy += 8)
        if (bx + yy < Cc && by + x < R)
            out[(size_t)(bx + yy) * R + by + x] = t[x][yy];
}

// ---------------------------------------------------------------------------
// Fused kc builder: one block per jrow, all 32 batches.
// kc[b][jrow][c] bf16 = sk[jrow][c] + sum_r a[b,v,r]*catBK[(v*8+r)*32+slot][c]
// catBK rows staged in LDS ONCE (vs 32x re-read before).
// ---------------------------------------------------------------------------
__global__ __launch_bounds__(256) void build_kc2(
    const float* __restrict__ sk, const float* __restrict__ catBK,
    const float* __restrict__ cat_A, const int* __restrict__ cat_ids,
    u16* __restrict__ kc)
{
    __shared__ float bk[8][1024];   // 32KB
    __shared__ float skr[1024];     // 4KB
    __shared__ float aS[32][8];     // 1KB
    const int jrow = blockIdx.x;
    const int v = jrow >> 5, slot = jrow & 31;
    const int tid = threadIdx.x;

    for (int idx = tid; idx < 2048; idx += 256) {
        int r = idx >> 8, c4 = (idx & 255) << 2;
        *(float4*)&bk[r][c4] =
            *(const float4*)(catBK + (size_t)((v * 8 + r) * 32 + slot) * 1024 + c4);
    }
    *(float4*)&skr[tid << 2] = *(const float4*)(sk + (size_t)jrow * 1024 + (tid << 2));
    {
        int b = tid >> 3, r = tid & 7;
        int cid = cat_ids[b]; if (cid < 0) cid = 0;
        aS[b][r] = cat_A[(cid * 10 + v) * 8 + r];
    }
    __syncthreads();

    const int c = tid << 2;
    const float4 base = *(const float4*)&skr[c];
    for (int b = 0; b < 32; ++b) {
        float4 acc = base;
#pragma unroll
        for (int r = 0; r < 8; ++r) {
            const float a = aS[b][r];
            const float4 bv = *(const float4*)&bk[r][c];
            acc.x = fmaf(a, bv.x, acc.x);
            acc.y = fmaf(a, bv.y, acc.y);
            acc.z = fmaf(a, bv.z, acc.z);
            acc.w = fmaf(a, bv.w, acc.w);
        }
        uint2 pk;
        pk.x = (unsigned)f2bf(acc.x) | ((unsigned)f2bf(acc.y) << 16);
        pk.y = (unsigned)f2bf(acc.z) | ((unsigned)f2bf(acc.w) << 16);
        *(uint2*)(kc + ((size_t)b * 320 + jrow) * 1024 + c) = pk;
    }
}

// ---------------------------------------------------------------------------
// Fused vcT builder: one block per channel c, all 32 batches.
// vcT[b][c][j] bf16 = svT[c][j] + sum_r a[b,v,r]*catBVT[c][(v*8+r)*32+slot]
// ---------------------------------------------------------------------------
__global__ __launch_bounds__(320) void build_vcT2(
    const float* __restrict__ svT, const float* __restrict__ catBVT,
    const float* __restrict__ cat_A, const int* __restrict__ cat_ids,
    u16* __restrict__ vcT)
{
    __shared__ float rowS[2560];    // 10KB
    __shared__ float svr[320];
    __shared__ float aS[32][80];    // 10KB
    const int c = blockIdx.x;
    const int tid = threadIdx.x;

    for (int idx = tid; idx < 2560; idx += 320)
        rowS[idx] = catBVT[(size_t)c * 2560 + idx];
    svr[tid] = svT[(size_t)c * 320 + tid];
    for (int idx = tid; idx < 2560; idx += 320) {
        int b = idx / 80, t = idx - b * 80;
        int cid = cat_ids[b]; if (cid < 0) cid = 0;
        aS[b][t] = cat_A[cid * 80 + t];
    }
    __syncthreads();

    const int j = tid, v = j >> 5, slot = j & 31;
    const float base = svr[j];
    const float* rp = &rowS[v * 256 + slot];
    for (int b = 0; b < 32; ++b) {
        float acc = base;
        const float* ap = &aS[b][v * 8];
#pragma unroll
        for (int r = 0; r < 8; ++r)
            acc = fmaf(ap[r], rp[r * 32], acc);
        vcT[((size_t)b * 1024 + c) * 320 + j] = f2bf(acc);
    }
}

// ---------------------------------------------------------------------------
// cb[0:64] = kb1, cb[64:128] = vb1
// ---------------------------------------------------------------------------
__global__ void concat_bias(const float* __restrict__ a,
                            const float* __restrict__ b, float* __restrict__ o)
{
    int t = threadIdx.x;
    if (t < 64) o[t] = a[t];
    else if (t < 128) o[t] = b[t - 64];
}

__global__ void tail_zero(float* p)
{
    if (threadIdx.x < 2) p[threadIdx.x] = 0.f;
}

// ---------------------------------------------------------------------------
extern "C" void kernel_launch(void* const* d_in, const int* in_sizes, int n_in,
                              void* d_out, int out_size, void* d_ws, size_t ws_size,
                              hipStream_t stream)
{
    (void)in_sizes; (void)n_in;
    const float* x         = (const float*)d_in[0];
    const int*   cat_ids   = (const int*)  d_in[1];
    const float* sm        = (const float*)d_in[2];
    const float* cat_A     = (const float*)d_in[3];
    const float* cat_B     = (const float*)d_in[4];
    const float* cat_emb   = (const float*)d_in[5];
    const float* scale_emb = (const float*)d_in[6];
    const float* Wq        = (const float*)d_in[7];
    const float* Wk        = (const float*)d_in[8];
    const float* Wv        = (const float*)d_in[9];
    const float* aW1       = (const float*)d_in[10];
    const float* ab1       = (const float*)d_in[11];
    const float* aW2       = (const float*)d_in[12];
    const float* ab2       = (const float*)d_in[13];
    const float* kW1       = (const float*)d_in[14];
    const float* kb1       = (const float*)d_in[15];
    const float* kW2       = (const float*)d_in[16];
    const float* kb2       = (const float*)d_in[17];
    const float* vW1       = (const float*)d_in[18];
    const float* vb1       = (const float*)d_in[19];
    const float* vW2       = (const float*)d_in[20];
    const float* vb2       = (const float*)d_in[21];
    const float* gk        = (const float*)d_in[22];
    const float* gv        = (const float*)d_in[23];
    const float* log_temp  = (const float*)d_in[24];

    float* out   = (float*)d_out;
    float* memb  = out;                          // mem_bf16 then fp32 mem_k
    float* outv  = out + (size_t)21760 * 1024;   // mem_v region (hosts query_bf first)

    // ---- workspace layout (floats) ----
    float* w      = (float*)d_ws;
    u16*   kc_bf  = (u16*)w;                     // [0, 5,242,880)
    u16*   vcT_bf = (u16*)(w + 5242880);         // [5,242,880, 10,485,760)
    float* sk     = w + 10485760;                // 327,680
    float* sv     = w + 10813440;                // 327,680
    float* svT    = w + 11141120;                // 327,680
    u16*   sk_bf  = (u16*)(w + 11468800);        // 163,840 f-equiv
    u16*   svT_bf = (u16*)(w + 11632640);        // 163,840 f-equiv
    float* alph   = w + 11796480;                // 21,760
    float* logits = w + 11859200;                // 13,926,400 (ends 25,785,600)
    // tail region (alpha-path statics), after logits:
    float* tail0  = w + 25785600;
    u16*   aW1topT = (u16*)tail0;                // 65,536 f each
    u16*   aW1midT = (u16*)(tail0 + 65536);
    u16*   aW1botT = (u16*)(tail0 + 131072);
    float* ceW    = tail0 + 196608;              // 22*128
    float* seW    = tail0 + 199424;              // 10*128
    float* cb     = tail0 + 200704;              // 128
    u16*   h_bf   = (u16*)(tail0 + 200832);      // 1,392,640 f (ends w+27,379,072)
    u16*   catB_bf = (u16*)(w + 27379072);       // 1,310,720 f (ends 28,689,792)
    u16*   sm_bf  = (u16*)(w + 28689792);        // 163,840 f  (ends 28,853,632)
    u16*   ce_bf  = (u16*)(w + 28853632);        // 11,264 f   (22x1024 bf16)
    u16*   se_bf  = (u16*)(w + 28864896);        // 5,120 f    (10x1024 bf16)
    if (ws_size < (size_t)29881600 * 4) return;
    if (out_size < 2 * 21760 * 1024 + 2) return;

    // --- overlays (lifetime-disjoint with their hosts) ---
    u16*   x_bf   = (u16*)logits;                // dead before gemm256_logits
    float* bufA   = logits + 5570560;            // catBK  2,621,440
    float* bufB   = bufA + 2621440;              // catBV  2,621,440
    float* catBVT = bufB + 2621440;              // 2,621,440
    u16*   WqT    = (u16*)w;                     // dead before build_kc2
    u16*   WkT    = WqT + 1048576;
    u16*   WvT    = WkT + 1048576;
    u16*   kW1T   = (u16*)sv;                    // written after sv consumed
    u16*   vW1T   = kW1T + 65536;                // contiguous => [128][1024]
    u16*   kW2T   = vW1T + 65536;
    u16*   vW2T   = kW2T + 65536;
    u16*   bufAB_bf = (u16*)w;                   // [21760][128] bf16, <= kc region
    u16*   mem_bf = (u16*)memb;                  // bf16 mem in d_out first half
    u16*   query_bf = (u16*)outv;                // dead before final mem_v gemm

    const dim3 blk256(256);
    const dim3 blk512(512);

    // 0. casts / weight transposes (tcast grid = (Cc/32, R/32))
    castbf<<<dim3(2048), blk256, 0, stream>>>(x, x_bf, 21760 * 1024 / 4);
    castbf<<<dim3(320), blk256, 0, stream>>>(sm, sm_bf, 320 * 1024 / 4);
    castbf<<<dim3(2048), blk256, 0, stream>>>(cat_B, catB_bf, 2560 * 1024 / 4);
    castbf<<<dim3(22), blk256, 0, stream>>>(cat_emb, ce_bf, 22 * 1024 / 4);
    castbf<<<dim3(10), blk256, 0, stream>>>(scale_emb, se_bf, 10 * 1024 / 4);
    tcast<<<dim3(32, 32), blk256, 0, stream>>>(Wq, WqT, 1024, 1024);
    tcast<<<dim3(32, 32), blk256, 0, stream>>>(Wk, WkT, 1024, 1024);
    tcast<<<dim3(32, 32), blk256, 0, stream>>>(Wv, WvT, 1024, 1024);
    tcast<<<dim3(4, 32), blk256, 0, stream>>>(aW1,              aW1topT, 1024, 128);
    tcast<<<dim3(4, 32), blk256, 0, stream>>>(aW1 + 1024 * 128, aW1midT, 1024, 128);
    tcast<<<dim3(4, 32), blk256, 0, stream>>>(aW1 + 2048 * 128, aW1botT, 1024, 128);

    // 1. projections (256-tile MFMA); grid = (n_blocks, m_blocks)
    gemm256<1><<<dim3(4, 85), blk512, 0, stream>>>(x_bf,    WqT, (float*)query_bf, 21760, 1024, 1024, 1024, nullptr, nullptr);
    gemm256<0><<<dim3(4, 2),  blk512, 0, stream>>>(sm_bf,   WkT, sk,   320,  1024, 1024, 1024, nullptr, nullptr);
    gemm256<0><<<dim3(4, 2),  blk512, 0, stream>>>(sm_bf,   WvT, sv,   320,  1024, 1024, 1024, nullptr, nullptr);
    gemm256<0><<<dim3(4, 10), blk512, 0, stream>>>(catB_bf, WkT, bufA, 2560, 1024, 1024, 1024, nullptr, nullptr);
    gemm256<0><<<dim3(4, 10), blk512, 0, stream>>>(catB_bf, WvT, bufB, 2560, 1024, 1024, 1024, nullptr, nullptr);

    // 1b. alpha-path statics (tiny, 128-tile)
    gemm_mfma<0><<<dim3(1, 1), blk256, 0, stream>>>(ce_bf, aW1midT, ceW, 22, 128, 1024, 1024, nullptr, nullptr);
    gemm_mfma<0><<<dim3(1, 1), blk256, 0, stream>>>(se_bf, aW1botT, seW, 10, 128, 1024, 1024, ab1, nullptr);

    // 2. derived key/value layouts
    castbf<<<dim3(320), blk256, 0, stream>>>(sk, sk_bf, 320 * 1024 / 4);
    transpose32<<<dim3(32, 10), blk256, 0, stream>>>(sv, svT, 320, 1024);
    tcast<<<dim3(32, 10), blk256, 0, stream>>>(sv, svT_bf, 320, 1024);
    transpose32<<<dim3(32, 80), blk256, 0, stream>>>(bufB, catBVT, 2560, 1024);
    // small head-weight transposes AFTER sv is consumed (they overlay sv)
    tcast<<<dim3(2, 32), blk256, 0, stream>>>(kW1, kW1T, 1024, 64);
    tcast<<<dim3(2, 32), blk256, 0, stream>>>(vW1, vW1T, 1024, 64);
    tcast<<<dim3(32, 2), blk256, 0, stream>>>(kW2, kW2T, 64, 1024);
    tcast<<<dim3(32, 2), blk256, 0, stream>>>(vW2, vW2T, 64, 1024);
    concat_bias<<<dim3(1), dim3(128), 0, stream>>>(kb1, vb1, cb);

    // 3. fused per-batch low-rank K/V builders (catB rows staged once)
    build_kc2<<<dim3(320), blk256, 0, stream>>>(sk, bufA, cat_A, cat_ids, kc_bf);
    build_vcT2<<<dim3(1024), dim3(320), 0, stream>>>(svT, catBVT, cat_A, cat_ids, vcT_bf);

    // 4. alpha gate (MFMA hidden + tiny reduce)
    gemm_halpha<<<dim3(170), blk256, 0, stream>>>(query_bf, aW1topT, ceW, seW, cat_ids, h_bf);
    alpha_reduce<<<dim3(5440), blk256, 0, stream>>>(h_bf, aW2, ab2, cat_ids, alph);

    // 5. attention as MFMA GEMMs: logits -> masked softmax (P in-place) -> PV
    gemm256_logits<<<dim3(3, 3, NB), blk512, 0, stream>>>(query_bf, sk_bf, kc_bf, logits);
    softmax_kernel<<<dim3(170, NB), blk256, 0, stream>>>(logits, alph, log_temp);
    gemm256_pv<<<dim3(4, 3, NB), blk512, 0, stream>>>((const u16*)logits, svT_bf, vcT_bf, mem_bf);

    // 6. final low-rank projections: fused bf16 stage-1 (N=128), two stage-2
    gemm_mfma<1><<<dim3(1, 170), blk256, 0, stream>>>(mem_bf, kW1T, (float*)bufAB_bf, 21760, 128, 1024, 1024, cb, nullptr);
    gemm256<0><<<dim3(4, 85), blk512, 0, stream>>>(bufAB_bf,      kW2T, memb, 21760, 1024, 64, 128, kb2, gk);
    gemm256<0><<<dim3(4, 85), blk512, 0, stream>>>(bufAB_bf + 64, vW2T, outv, 21760, 1024, 64, 128, vb2, gv);

    tail_zero<<<1, 64, 0, stream>>>(out + (size_t)2 * 21760 * 1024);
}

// Round 6
// 897.569 us; speedup vs baseline: 1.1067x; 1.1067x over previous
//
#include <hip/hip_runtime.h>
#include <math.h>

// Problem constants
#define NB 32          // batch
#define NC 1024        // channels
#define LTOT 680       // total tokens per batch

typedef unsigned short u16;
typedef __bf16 bf16x8 __attribute__((ext_vector_type(8)));
typedef float floatx4 __attribute__((ext_vector_type(4)));

__device__ __forceinline__ u16 f2bf(float f)
{
    union { float f; unsigned u; } v; v.f = f;
    unsigned u = v.u;
    u += 0x7FFFu + ((u >> 16) & 1u);   // RNE
    return (u16)(u >> 16);
}

__device__ __forceinline__ float bf2f(unsigned u)
{
    union { unsigned u; float f; } v; v.u = u << 16; return v.f;
}

// ---------------------------------------------------------------------------
// Async global->LDS 16B copy. LDS dest is wave-uniform base + lane*16 (HW
// semantics); global src is per-lane.
// ---------------------------------------------------------------------------
__device__ __forceinline__ void gload16(const u16* g, u16* l)
{
    typedef __attribute__((address_space(1))) const void gv_t;
    typedef __attribute__((address_space(3))) void lv_t;
    __builtin_amdgcn_global_load_lds(
        (gv_t*)(unsigned long long)(const void*)g,
        (lv_t*)(unsigned int)(unsigned long long)(void*)l,
        16, 0, 0);
}

// slot decode for [rows x 32k] frag-order tiles (BK=32):
// slot = (row>>4)*64 + cq*16 + (row&15), cq in [0,4)
__device__ __forceinline__ void slot_decode256(int s, int* prow, int* pcq)
{
    *prow = ((s >> 6) << 4) | (s & 15);
    *pcq  = (s >> 4) & 3;
}

// Counted waits: fl = tiles (4 loads/thread each) allowed to stay in flight.
__device__ __forceinline__ void wait_tiles(int fl)
{
    if (fl >= 3)      asm volatile("s_waitcnt vmcnt(12)" ::: "memory");
    else if (fl == 2) asm volatile("s_waitcnt vmcnt(8)"  ::: "memory");
    else if (fl == 1) asm volatile("s_waitcnt vmcnt(4)"  ::: "memory");
    else              asm volatile("s_waitcnt vmcnt(0)"  ::: "memory");
}
#define BAR()       __builtin_amdgcn_s_barrier()
#define SCHEDB()    __builtin_amdgcn_sched_barrier(0)

// ===========================================================================
// 256x256-tile bf16 MFMA GEMM, BK=32, 512 threads = 8 waves (2m x 4n),
// per-wave output 128x64 (acc[8][4]).  4-buffer LDS (128KB), depth-3
// counted-vmcnt pipeline (3 tiles = 96KB in flight per block).
// OUTBF=1: C stored bf16.  lda = A row stride.  K multiple of 32.
// ===========================================================================
template<int OUTBF>
__global__ __launch_bounds__(512) void gemm256d(
    const u16* __restrict__ A, const u16* __restrict__ BT,
    float* __restrict__ C, int M, int N, int K, int lda,
    const float* __restrict__ bias, const float* __restrict__ scale_logit)
{
    __shared__ __align__(16) u16 As[4][8192];   // 64KB
    __shared__ __align__(16) u16 Bs[4][8192];   // 64KB

    const int tid  = threadIdx.x;
    const int m0   = blockIdx.y << 8;
    const int n0   = blockIdx.x << 8;
    const int wave = tid >> 6;
    const int lane = tid & 63;
    const int mh   = wave & 1;
    const int nh   = wave >> 1;
    const int lbase = (wave << 6) * 8;

    const u16* aSrc[2];
    const u16* bSrc[2];
#pragma unroll
    for (int p = 0; p < 2; ++p) {
        int s = tid + (p << 9), row, cq;
        slot_decode256(s, &row, &cq);
        int gr = m0 + row; if (gr > M - 1) gr = M - 1;
        aSrc[p] = A + (size_t)gr * lda + (cq << 3);
        int gn = n0 + row; if (gn > N - 1) gn = N - 1;
        bSrc[p] = BT + (size_t)gn * K + (cq << 3);
    }

    floatx4 acc[8][4];
#pragma unroll
    for (int i = 0; i < 8; ++i)
#pragma unroll
        for (int j = 0; j < 4; ++j) acc[i][j] = (floatx4){0.f, 0.f, 0.f, 0.f};

    auto STAGE = [&](int tn) {
        const int kk = tn << 5;
        u16* da = &As[tn & 3][lbase];
        u16* db = &Bs[tn & 3][lbase];
#pragma unroll
        for (int p = 0; p < 2; ++p) gload16(aSrc[p] + kk, da + (p << 12));
#pragma unroll
        for (int p = 0; p < 2; ++p) gload16(bSrc[p] + kk, db + (p << 12));
    };

    const int nt = K >> 5;
    for (int pre = 0; pre < 3 && pre < nt; ++pre) STAGE(pre);

    for (int t = 0; t < nt; ++t) {
        if (t + 3 < nt) STAGE(t + 3);
        int fl = nt - 1 - t; if (fl > 3) fl = 3;
        wait_tiles(fl);
        BAR(); SCHEDB();
        const int cur = t & 3;
        {
            bf16x8 a[8], b[4];
#pragma unroll
            for (int i = 0; i < 8; ++i)
                a[i] = *(const bf16x8*)&As[cur][((((mh << 3) + i) << 6) + lane) * 8];
#pragma unroll
            for (int j = 0; j < 4; ++j)
                b[j] = *(const bf16x8*)&Bs[cur][((((nh << 2) + j) << 6) + lane) * 8];
#pragma unroll
            for (int i = 0; i < 8; ++i)
#pragma unroll
                for (int j = 0; j < 4; ++j)
                    acc[i][j] = __builtin_amdgcn_mfma_f32_16x16x32_bf16(a[i], b[j], acc[i][j], 0, 0, 0);
        }
        SCHEDB(); BAR();
    }

    float scale = 1.f;
    if (scale_logit) scale = 1.f / (1.f + __expf(-scale_logit[0]));
    const int col = lane & 15, rquad = lane >> 4;
#pragma unroll
    for (int i = 0; i < 8; ++i) {
#pragma unroll
        for (int j = 0; j < 4; ++j) {
#pragma unroll
            for (int r = 0; r < 4; ++r) {
                int gr = m0 + (mh << 7) + (i << 4) + (rquad << 2) + r;
                int gc = n0 + (nh << 6) + (j << 4) + col;
                if (gr < M && gc < N) {
                    float bb = bias ? bias[gc] : 0.f;
                    float val = scale * (acc[i][j][r] + bb);
                    if (OUTBF) ((u16*)C)[(size_t)gr * N + gc] = f2bf(val);
                    else       C[(size_t)gr * N + gc] = val;
                }
            }
        }
    }
}

// ---------------------------------------------------------------------------
// Batched logits GEMM (256-tile, depth-3): out[b][680][640] = Q_b @ [sk;kc_b]^T
// grid (3n, 3m, 32b), clamped/guarded.
// ---------------------------------------------------------------------------
__global__ __launch_bounds__(512) void gemm_logits(
    const u16* __restrict__ Q, const u16* __restrict__ skb,
    const u16* __restrict__ kcb, float* __restrict__ out)
{
    __shared__ __align__(16) u16 As[4][8192];
    __shared__ __align__(16) u16 Bs[4][8192];

    const int tid  = threadIdx.x;
    const int m0   = blockIdx.y << 8;
    const int n0   = blockIdx.x << 8;
    const int b    = blockIdx.z;
    const int wave = tid >> 6;
    const int lane = tid & 63;
    const int mh   = wave & 1;
    const int nh   = wave >> 1;
    const int lbase = (wave << 6) * 8;

    const u16* Ab = Q   + (size_t)b * 680 * 1024;
    const u16* KC = kcb + (size_t)b * 320 * 1024;

    const u16* aSrc[2];
    const u16* bSrc[2];
#pragma unroll
    for (int p = 0; p < 2; ++p) {
        int s = tid + (p << 9), row, cq;
        slot_decode256(s, &row, &cq);
        int gr = m0 + row; if (gr > 679) gr = 679;
        aSrc[p] = Ab + (size_t)gr * 1024 + (cq << 3);
        int gn = n0 + row; if (gn > 639) gn = 639;
        bSrc[p] = ((gn < 320) ? (skb + (size_t)gn * 1024)
                              : (KC + (size_t)(gn - 320) * 1024)) + (cq << 3);
    }

    floatx4 acc[8][4];
#pragma unroll
    for (int i = 0; i < 8; ++i)
#pragma unroll
        for (int j = 0; j < 4; ++j) acc[i][j] = (floatx4){0.f, 0.f, 0.f, 0.f};

    auto STAGE = [&](int tn) {
        const int kk = tn << 5;
        u16* da = &As[tn & 3][lbase];
        u16* db = &Bs[tn & 3][lbase];
#pragma unroll
        for (int p = 0; p < 2; ++p) gload16(aSrc[p] + kk, da + (p << 12));
#pragma unroll
        for (int p = 0; p < 2; ++p) gload16(bSrc[p] + kk, db + (p << 12));
    };

    for (int pre = 0; pre < 3; ++pre) STAGE(pre);

    for (int t = 0; t < 32; ++t) {
        if (t + 3 < 32) STAGE(t + 3);
        int fl = 31 - t; if (fl > 3) fl = 3;
        wait_tiles(fl);
        BAR(); SCHEDB();
        const int cur = t & 3;
        {
            bf16x8 a[8], bb[4];
#pragma unroll
            for (int i = 0; i < 8; ++i)
                a[i] = *(const bf16x8*)&As[cur][((((mh << 3) + i) << 6) + lane) * 8];
#pragma unroll
            for (int j = 0; j < 4; ++j)
                bb[j] = *(const bf16x8*)&Bs[cur][((((nh << 2) + j) << 6) + lane) * 8];
#pragma unroll
            for (int i = 0; i < 8; ++i)
#pragma unroll
                for (int j = 0; j < 4; ++j)
                    acc[i][j] = __builtin_amdgcn_mfma_f32_16x16x32_bf16(a[i], bb[j], acc[i][j], 0, 0, 0);
        }
        SCHEDB(); BAR();
    }

    const int col = lane & 15, rquad = lane >> 4;
#pragma unroll
    for (int i = 0; i < 8; ++i)
#pragma unroll
        for (int j = 0; j < 4; ++j)
#pragma unroll
            for (int r = 0; r < 4; ++r) {
                int gr = m0 + (mh << 7) + (i << 4) + (rquad << 2) + r;
                int gc = n0 + (nh << 6) + (j << 4) + col;
                if (gr < 680 && gc < 640)
                    out[((size_t)b * 680 + gr) * 640 + gc] = acc[i][j][r];
            }
}

// ---------------------------------------------------------------------------
// Batched PV GEMM (256-tile, depth-3): mem[b][680][1024] bf16 = P_b @ [sv;vc_b]
// A = P bf16, row stride 1280 u16.  grid (4n, 3m, 32b).  K=640 -> 20 tiles,
// tiles 0-9 read svT, 10-19 read vcT.
// ---------------------------------------------------------------------------
__global__ __launch_bounds__(512) void gemm_pv(
    const u16* __restrict__ P, const u16* __restrict__ svT,
    const u16* __restrict__ vcT, u16* __restrict__ out)
{
    __shared__ __align__(16) u16 As[4][8192];
    __shared__ __align__(16) u16 Bs[4][8192];

    const int tid  = threadIdx.x;
    const int m0   = blockIdx.y << 8;
    const int n0   = blockIdx.x << 8;
    const int b    = blockIdx.z;
    const int wave = tid >> 6;
    const int lane = tid & 63;
    const int mh   = wave & 1;
    const int nh   = wave >> 1;
    const int lbase = (wave << 6) * 8;

    const u16* aSrc[2];
    const u16* bSrcS[2];
    const u16* bSrcC[2];
#pragma unroll
    for (int p = 0; p < 2; ++p) {
        int s = tid + (p << 9), row, cq;
        slot_decode256(s, &row, &cq);
        int gr = m0 + row; if (gr > 679) gr = 679;
        aSrc[p] = P + ((size_t)b * 680 + gr) * 1280 + (cq << 3);
        int gn = n0 + row;                    // < 1024 always
        bSrcS[p] = svT + (size_t)gn * 320 + (cq << 3);
        bSrcC[p] = vcT + ((size_t)b * 1024 + gn) * 320 + (cq << 3);
    }

    floatx4 acc[8][4];
#pragma unroll
    for (int i = 0; i < 8; ++i)
#pragma unroll
        for (int j = 0; j < 4; ++j) acc[i][j] = (floatx4){0.f, 0.f, 0.f, 0.f};

    auto STAGE = [&](int tn) {
        const int kk = tn << 5;
        u16* da = &As[tn & 3][lbase];
        u16* db = &Bs[tn & 3][lbase];
#pragma unroll
        for (int p = 0; p < 2; ++p) gload16(aSrc[p] + kk, da + (p << 12));
#pragma unroll
        for (int p = 0; p < 2; ++p) {
            const u16* bp = (tn < 10) ? (bSrcS[p] + kk) : (bSrcC[p] + (kk - 320));
            gload16(bp, db + (p << 12));
        }
    };

    for (int pre = 0; pre < 3; ++pre) STAGE(pre);

    for (int t = 0; t < 20; ++t) {
        if (t + 3 < 20) STAGE(t + 3);
        int fl = 19 - t; if (fl > 3) fl = 3;
        wait_tiles(fl);
        BAR(); SCHEDB();
        const int cur = t & 3;
        {
            bf16x8 a[8], bb[4];
#pragma unroll
            for (int i = 0; i < 8; ++i)
                a[i] = *(const bf16x8*)&As[cur][((((mh << 3) + i) << 6) + lane) * 8];
#pragma unroll
            for (int j = 0; j < 4; ++j)
                bb[j] = *(const bf16x8*)&Bs[cur][((((nh << 2) + j) << 6) + lane) * 8];
#pragma unroll
            for (int i = 0; i < 8; ++i)
#pragma unroll
                for (int j = 0; j < 4; ++j)
                    acc[i][j] = __builtin_amdgcn_mfma_f32_16x16x32_bf16(a[i], bb[j], acc[i][j], 0, 0, 0);
        }
        SCHEDB(); BAR();
    }

    const int col = lane & 15, rquad = lane >> 4;
#pragma unroll
    for (int i = 0; i < 8; ++i)
#pragma unroll
        for (int j = 0; j < 4; ++j)
#pragma unroll
            for (int r = 0; r < 4; ++r) {
                int gr = m0 + (mh << 7) + (i << 4) + (rquad << 2) + r;
                int gc = n0 + (nh << 6) + (j << 4) + col;
                if (gr < 680)
                    out[((size_t)b * 680 + gr) * 1024 + gc] = f2bf(acc[i][j][r]);
            }
}

// ===========================================================================
// 128x128-tile GEMM, BK=32, 256 threads = 4 waves (2x2), 4-buffer depth-3
// pipeline (64KB LDS -> 2 blocks/CU).  For small-M/N work.
// ===========================================================================
template<int OUTBF>
__global__ __launch_bounds__(256) void gemm128d(
    const u16* __restrict__ A, const u16* __restrict__ BT,
    float* __restrict__ C, int M, int N, int K, int lda,
    const float* __restrict__ bias, const float* __restrict__ scale_logit)
{
    __shared__ __align__(16) u16 As[4][4096];   // 32KB
    __shared__ __align__(16) u16 Bs[4][4096];   // 32KB

    const int tid  = threadIdx.x;
    const int m0   = blockIdx.y << 7;
    const int n0   = blockIdx.x << 7;
    const int wave = tid >> 6;
    const int lane = tid & 63;
    const int mh   = wave & 1;
    const int nh   = wave >> 1;
    const int lbase = (wave << 6) * 8;

    const u16* aSrc[2];
    const u16* bSrc[2];
#pragma unroll
    for (int p = 0; p < 2; ++p) {
        int s = tid + (p << 8), row, cq;
        slot_decode256(s, &row, &cq);          // row < 128, cq < 4
        int gr = m0 + row; if (gr > M - 1) gr = M - 1;
        aSrc[p] = A + (size_t)gr * lda + (cq << 3);
        int gn = n0 + row; if (gn > N - 1) gn = N - 1;
        bSrc[p] = BT + (size_t)gn * K + (cq << 3);
    }

    floatx4 acc[4][4];
#pragma unroll
    for (int i = 0; i < 4; ++i)
#pragma unroll
        for (int j = 0; j < 4; ++j) acc[i][j] = (floatx4){0.f, 0.f, 0.f, 0.f};

    auto STAGE = [&](int tn) {
        const int kk = tn << 5;
        u16* da = &As[tn & 3][lbase];
        u16* db = &Bs[tn & 3][lbase];
#pragma unroll
        for (int p = 0; p < 2; ++p) gload16(aSrc[p] + kk, da + (p << 11));
#pragma unroll
        for (int p = 0; p < 2; ++p) gload16(bSrc[p] + kk, db + (p << 11));
    };

    const int nt = K >> 5;
    for (int pre = 0; pre < 3 && pre < nt; ++pre) STAGE(pre);

    for (int t = 0; t < nt; ++t) {
        if (t + 3 < nt) STAGE(t + 3);
        int fl = nt - 1 - t; if (fl > 3) fl = 3;
        wait_tiles(fl);
        BAR(); SCHEDB();
        const int cur = t & 3;
        {
            bf16x8 a[4], b[4];
#pragma unroll
            for (int i = 0; i < 4; ++i)
                a[i] = *(const bf16x8*)&As[cur][((((mh << 2) + i) << 6) + lane) * 8];
#pragma unroll
            for (int j = 0; j < 4; ++j)
                b[j] = *(const bf16x8*)&Bs[cur][((((nh << 2) + j) << 6) + lane) * 8];
#pragma unroll
            for (int i = 0; i < 4; ++i)
#pragma unroll
                for (int j = 0; j < 4; ++j)
                    acc[i][j] = __builtin_amdgcn_mfma_f32_16x16x32_bf16(a[i], b[j], acc[i][j], 0, 0, 0);
        }
        SCHEDB(); BAR();
    }

    float scale = 1.f;
    if (scale_logit) scale = 1.f / (1.f + __expf(-scale_logit[0]));
    const int col = lane & 15, rquad = lane >> 4;
#pragma unroll
    for (int i = 0; i < 4; ++i) {
#pragma unroll
        for (int j = 0; j < 4; ++j) {
#pragma unroll
            for (int r = 0; r < 4; ++r) {
                int gr = m0 + (mh << 6) + (i << 4) + (rquad << 2) + r;
                int gc = n0 + (nh << 6) + (j << 4) + col;
                if (gr < M && gc < N) {
                    float bb = bias ? bias[gc] : 0.f;
                    float val = scale * (acc[i][j][r] + bb);
                    if (OUTBF) ((u16*)C)[(size_t)gr * N + gc] = f2bf(val);
                    else       C[(size_t)gr * N + gc] = val;
                }
            }
        }
    }
}

// ---------------------------------------------------------------------------
// Alpha hidden GEMM (128-tile depth-3): h[21760][128] bf16 =
//   gelu( Q @ aW1_topT + ceW[cid[b]] + seW[isc(l)] )   (seW includes ab1)
// ---------------------------------------------------------------------------
__global__ __launch_bounds__(256) void gemm_halpha(
    const u16* __restrict__ Q, const u16* __restrict__ W,
    const float* __restrict__ ceW, const float* __restrict__ seW,
    const int* __restrict__ cat_ids, u16* __restrict__ h)
{
    __shared__ __align__(16) u16 As[4][4096];
    __shared__ __align__(16) u16 Bs[4][4096];

    const int tid  = threadIdx.x;
    const int m0   = blockIdx.x << 7;
    const int wave = tid >> 6;
    const int lane = tid & 63;
    const int mh   = wave & 1;
    const int nh   = wave >> 1;
    const int lbase = (wave << 6) * 8;

    const u16* aSrc[2];
    const u16* bSrc[2];
#pragma unroll
    for (int p = 0; p < 2; ++p) {
        int s = tid + (p << 8), row, cq;
        slot_decode256(s, &row, &cq);
        aSrc[p] = Q + (size_t)(m0 + row) * 1024 + (cq << 3);   // m0+row < 21760
        bSrc[p] = W + (size_t)row * 1024 + (cq << 3);          // row < 128 = N
    }

    floatx4 acc[4][4];
#pragma unroll
    for (int i = 0; i < 4; ++i)
#pragma unroll
        for (int j = 0; j < 4; ++j) acc[i][j] = (floatx4){0.f, 0.f, 0.f, 0.f};

    auto STAGE = [&](int tn) {
        const int kk = tn << 5;
        u16* da = &As[tn & 3][lbase];
        u16* db = &Bs[tn & 3][lbase];
#pragma unroll
        for (int p = 0; p < 2; ++p) gload16(aSrc[p] + kk, da + (p << 11));
#pragma unroll
        for (int p = 0; p < 2; ++p) gload16(bSrc[p] + kk, db + (p << 11));
    };

    for (int pre = 0; pre < 3; ++pre) STAGE(pre);

    for (int t = 0; t < 32; ++t) {
        if (t + 3 < 32) STAGE(t + 3);
        int fl = 31 - t; if (fl > 3) fl = 3;
        wait_tiles(fl);
        BAR(); SCHEDB();
        const int cur = t & 3;
        {
            bf16x8 a[4], bb[4];
#pragma unroll
            for (int i = 0; i < 4; ++i)
                a[i] = *(const bf16x8*)&As[cur][((((mh << 2) + i) << 6) + lane) * 8];
#pragma unroll
            for (int j = 0; j < 4; ++j)
                bb[j] = *(const bf16x8*)&Bs[cur][((((nh << 2) + j) << 6) + lane) * 8];
#pragma unroll
            for (int i = 0; i < 4; ++i)
#pragma unroll
                for (int j = 0; j < 4; ++j)
                    acc[i][j] = __builtin_amdgcn_mfma_f32_16x16x32_bf16(a[i], bb[j], acc[i][j], 0, 0, 0);
        }
        SCHEDB(); BAR();
    }

    const int se_[9] = {1,5,14,30,55,91,155,255,424};
    const int col = lane & 15, rquad = lane >> 4;
#pragma unroll
    for (int i = 0; i < 4; ++i) {
#pragma unroll
        for (int r = 0; r < 4; ++r) {
            int gr = m0 + (mh << 6) + (i << 4) + (rquad << 2) + r;
            int b  = gr / 680;
            int l  = gr - b * 680;
            int isc = 0;
#pragma unroll
            for (int k = 0; k < 9; ++k) if (l >= se_[k]) isc = k + 1;
            int cid = cat_ids[b]; if (cid < 0) cid = 0;
            const float* cw = ceW + cid * 128;
            const float* sw = seW + isc * 128;
#pragma unroll
            for (int j = 0; j < 4; ++j) {
                int gc = (nh << 6) + (j << 4) + col;
                float val = acc[i][j][r] + cw[gc] + sw[gc];
                float g = 0.5f * val * (1.0f + erff(val * 0.70710678118654752f));
                h[(size_t)gr * 128 + gc] = f2bf(g);
            }
        }
    }
}

// ---------------------------------------------------------------------------
// alpha[row] = valid ? sigmoid( dot(h[row], aW2) + ab2 ) : 0.
// ---------------------------------------------------------------------------
__global__ __launch_bounds__(256) void alpha_reduce(
    const u16* __restrict__ h, const float* __restrict__ aW2,
    const float* __restrict__ ab2, const int* __restrict__ cat_ids,
    float* __restrict__ alpha)
{
    const int wave = threadIdx.x >> 6;
    const int lane = threadIdx.x & 63;
    const int row  = (blockIdx.x << 2) + wave;   // < 21760 exact

    const unsigned pk = *(const unsigned*)(h + (size_t)row * 128 + (lane << 1));
    float s = bf2f(pk) * aW2[lane << 1] + bf2f(pk >> 16) * aW2[(lane << 1) + 1];
#pragma unroll
    for (int k = 32; k >= 1; k >>= 1) s += __shfl_xor(s, k);
    if (lane == 0) {
        int b = row / 680;
        float al = 0.f;
        if (cat_ids[b] >= 0) al = 1.f / (1.f + expf(-(s + ab2[0])));
        alpha[row] = al;
    }
}

// ---------------------------------------------------------------------------
// Masked dual softmax, one wave per token row; folds alpha into P.
// Reads logits row [640] fp32, writes P row [640] bf16 IN PLACE.
// ---------------------------------------------------------------------------
__global__ __launch_bounds__(256) void softmax_kernel(
    float* __restrict__ logits, const float* __restrict__ alpha,
    const float* __restrict__ log_temp)
{
    const int tid  = threadIdx.x;
    const int w    = tid >> 6;
    const int lane = tid & 63;
    const int b    = blockIdx.y;
    const int l    = (blockIdx.x << 2) + w;     // 680 = 170*4, exact

    const int se[10] = {1,5,14,30,55,91,155,255,424,680};
    int isc = 0;
#pragma unroll
    for (int k = 0; k < 9; ++k) if (l >= se[k]) isc = k + 1;
    const int NK = (isc + 1) << 5;

    float temp = __expf(log_temp[0]);
    temp = fminf(fmaxf(temp, 0.05f), 1.0f);
    const float Ksc = 0.03125f / temp;

    float* row = logits + ((size_t)b * 680 + l) * 640;

    float ls[5], lc[5];
#pragma unroll
    for (int u = 0; u < 5; ++u) {
        int j = lane + (u << 6);
        bool v = j < NK;
        ls[u] = v ? row[j]       : -1e30f;
        lc[u] = v ? row[320 + j] : -1e30f;
    }
    float mxs = -1e30f, mxc = -1e30f;
#pragma unroll
    for (int u = 0; u < 5; ++u) { mxs = fmaxf(mxs, ls[u]); mxc = fmaxf(mxc, lc[u]); }
#pragma unroll
    for (int k = 32; k >= 1; k >>= 1) {
        mxs = fmaxf(mxs, __shfl_xor(mxs, k));
        mxc = fmaxf(mxc, __shfl_xor(mxc, k));
    }
    float es[5], ec[5], ss = 0.f, sc = 0.f;
#pragma unroll
    for (int u = 0; u < 5; ++u) {
        int j = lane + (u << 6);
        bool v = j < NK;
        es[u] = v ? __expf((ls[u] - mxs) * Ksc) : 0.f;
        ec[u] = v ? __expf((lc[u] - mxc) * Ksc) : 0.f;
        ss += es[u]; sc += ec[u];
    }
#pragma unroll
    for (int k = 32; k >= 1; k >>= 1) {
        ss += __shfl_xor(ss, k);
        sc += __shfl_xor(sc, k);
    }
    const float al = alpha[b * LTOT + l];
    const float wS = (1.f - al) / ss;
    const float wC = al / sc;

    u16* po = (u16*)row;
#pragma unroll
    for (int u = 0; u < 5; ++u) {
        int j = lane + (u << 6);
        po[j]       = f2bf(es[u] * wS);
        po[320 + j] = f2bf(ec[u] * wC);
    }
}

// ---------------------------------------------------------------------------
// fp32 elementwise -> bf16 (n4 = element count / 4)
// ---------------------------------------------------------------------------
__global__ __launch_bounds__(256) void castbf(
    const float* __restrict__ in, u16* __restrict__ out, int n4)
{
    int i = blockIdx.x * 256 + threadIdx.x;
    const int stride = gridDim.x * 256;
    for (; i < n4; i += stride) {
        const float4 v = ((const float4*)in)[i];
        uint2 o;
        o.x = (unsigned)f2bf(v.x) | ((unsigned)f2bf(v.y) << 16);
        o.y = (unsigned)f2bf(v.z) | ((unsigned)f2bf(v.w) << 16);
        ((uint2*)out)[i] = o;
    }
}

// ---------------------------------------------------------------------------
// transpose + cast: out[Cc][R] bf16 = in[R][Cc]^T. grid (ceil(Cc/32), ceil(R/32))
// ---------------------------------------------------------------------------
__global__ __launch_bounds__(256) void tcast(
    const float* __restrict__ in, u16* __restrict__ out, int R, int Cc)
{
    __shared__ float t[32][33];
    const int bx = blockIdx.x * 32;   // Cc
    const int by = blockIdx.y * 32;   // R
    const int x = threadIdx.x & 31;
    const int y0 = threadIdx.x >> 5;
#pragma unroll
    for (int yy = y0; yy < 32; yy += 8)
        t[yy][x] = (by + yy < R && bx + x < Cc)
                 ? in[(size_t)(by + yy) * Cc + bx + x] : 0.f;
    __syncthreads();
#pragma unroll
    for (int yy = y0; yy < 32; yy += 8)
        if (bx + yy < Cc && by + x < R)
            out[(size_t)(bx + yy) * R + by + x] = f2bf(t[x][yy]);
}

// ---------------------------------------------------------------------------
// 32x32 fp32 transpose, same grid convention, guarded.
// ---------------------------------------------------------------------------
__global__ __launch_bounds__(256) void transpose32(
    const float* __restrict__ in, float* __restrict__ out, int R, int Cc)
{
    __shared__ float t[32][33];
    const int bx = blockIdx.x * 32;
    const int by = blockIdx.y * 32;
    const int x = threadIdx.x & 31;
    const int y0 = threadIdx.x >> 5;
#pragma unroll
    for (int yy = y0; yy < 32; yy += 8)
        t[yy][x] = (by + yy < R && bx + x < Cc)
                 ? in[(size_t)(by + yy) * Cc + bx + x] : 0.f;
    __syncthreads();
#pragma unroll
    for (int yy = y0; yy < 32; yy += 8)
        if (bx + yy < Cc && by + x < R)
            out[(size_t)(bx + yy) * R + by + x] = t[x][yy];
}

// ---------------------------------------------------------------------------
// Fused kc builder: one block per jrow, all 32 batches; catBK staged once.
// ---------------------------------------------------------------------------
__global__ __launch_bounds__(256) void build_kc2(
    const float* __restrict__ sk, const float* __restrict__ catBK,
    const float* __restrict__ cat_A, const int* __restrict__ cat_ids,
    u16* __restrict__ kc)
{
    __shared__ float bk[8][1024];   // 32KB
    __shared__ float skr[1024];     // 4KB
    __shared__ float aS[32][8];     // 1KB
    const int jrow = blockIdx.x;
    const int v = jrow >> 5, slot = jrow & 31;
    const int tid = threadIdx.x;

    for (int idx = tid; idx < 2048; idx += 256) {
        int r = idx >> 8, c4 = (idx & 255) << 2;
        *(float4*)&bk[r][c4] =
            *(const float4*)(catBK + (size_t)((v * 8 + r) * 32 + slot) * 1024 + c4);
    }
    *(float4*)&skr[tid << 2] = *(const float4*)(sk + (size_t)jrow * 1024 + (tid << 2));
    {
        int b = tid >> 3, r = tid & 7;
        int cid = cat_ids[b]; if (cid < 0) cid = 0;
        aS[b][r] = cat_A[(cid * 10 + v) * 8 + r];
    }
    __syncthreads();

    const int c = tid << 2;
    const float4 base = *(const float4*)&skr[c];
    for (int b = 0; b < 32; ++b) {
        float4 acc = base;
#pragma unroll
        for (int r = 0; r < 8; ++r) {
            const float a = aS[b][r];
            const float4 bv = *(const float4*)&bk[r][c];
            acc.x = fmaf(a, bv.x, acc.x);
            acc.y = fmaf(a, bv.y, acc.y);
            acc.z = fmaf(a, bv.z, acc.z);
            acc.w = fmaf(a, bv.w, acc.w);
        }
        uint2 pk;
        pk.x = (unsigned)f2bf(acc.x) | ((unsigned)f2bf(acc.y) << 16);
        pk.y = (unsigned)f2bf(acc.z) | ((unsigned)f2bf(acc.w) << 16);
        *(uint2*)(kc + ((size_t)b * 320 + jrow) * 1024 + c) = pk;
    }
}

// ---------------------------------------------------------------------------
// Fused vcT builder: one block per channel c, all 32 batches.
// ---------------------------------------------------------------------------
__global__ __launch_bounds__(320) void build_vcT2(
    const float* __restrict__ svT, const float* __restrict__ catBVT,
    const float* __restrict__ cat_A, const int* __restrict__ cat_ids,
    u16* __restrict__ vcT)
{
    __shared__ float rowS[2560];    // 10KB
    __shared__ float svr[320];
    __shared__ float aS[32][80];    // 10KB
    const int c = blockIdx.x;
    const int tid = threadIdx.x;

    for (int idx = tid; idx < 2560; idx += 320)
        rowS[idx] = catBVT[(size_t)c * 2560 + idx];
    svr[tid] = svT[(size_t)c * 320 + tid];
    for (int idx = tid; idx < 2560; idx += 320) {
        int b = idx / 80, t = idx - b * 80;
        int cid = cat_ids[b]; if (cid < 0) cid = 0;
        aS[b][t] = cat_A[cid * 80 + t];
    }
    __syncthreads();

    const int j = tid, v = j >> 5, slot = j & 31;
    const float base = svr[j];
    const float* rp = &rowS[v * 256 + slot];
    for (int b = 0; b < 32; ++b) {
        float acc = base;
        const float* ap = &aS[b][v * 8];
#pragma unroll
        for (int r = 0; r < 8; ++r)
            acc = fmaf(ap[r], rp[r * 32], acc);
        vcT[((size_t)b * 1024 + c) * 320 + j] = f2bf(acc);
    }
}

// ---------------------------------------------------------------------------
// cb[0:64] = kb1, cb[64:128] = vb1
// ---------------------------------------------------------------------------
__global__ void concat_bias(const float* __restrict__ a,
                            const float* __restrict__ b, float* __restrict__ o)
{
    int t = threadIdx.x;
    if (t < 64) o[t] = a[t];
    else if (t < 128) o[t] = b[t - 64];
}

__global__ void tail_zero(float* p)
{
    if (threadIdx.x < 2) p[threadIdx.x] = 0.f;
}

// ---------------------------------------------------------------------------
extern "C" void kernel_launch(void* const* d_in, const int* in_sizes, int n_in,
                              void* d_out, int out_size, void* d_ws, size_t ws_size,
                              hipStream_t stream)
{
    (void)in_sizes; (void)n_in;
    const float* x         = (const float*)d_in[0];
    const int*   cat_ids   = (const int*)  d_in[1];
    const float* sm        = (const float*)d_in[2];
    const float* cat_A     = (const float*)d_in[3];
    const float* cat_B     = (const float*)d_in[4];
    const float* cat_emb   = (const float*)d_in[5];
    const float* scale_emb = (const float*)d_in[6];
    const float* Wq        = (const float*)d_in[7];
    const float* Wk        = (const float*)d_in[8];
    const float* Wv        = (const float*)d_in[9];
    const float* aW1       = (const float*)d_in[10];
    const float* ab1       = (const float*)d_in[11];
    const float* aW2       = (const float*)d_in[12];
    const float* ab2       = (const float*)d_in[13];
    const float* kW1       = (const float*)d_in[14];
    const float* kb1       = (const float*)d_in[15];
    const float* kW2       = (const float*)d_in[16];
    const float* kb2       = (const float*)d_in[17];
    const float* vW1       = (const float*)d_in[18];
    const float* vb1       = (const float*)d_in[19];
    const float* vW2       = (const float*)d_in[20];
    const float* vb2       = (const float*)d_in[21];
    const float* gk        = (const float*)d_in[22];
    const float* gv        = (const float*)d_in[23];
    const float* log_temp  = (const float*)d_in[24];

    float* out   = (float*)d_out;
    float* memb  = out;                          // mem_bf16 then fp32 mem_k
    float* outv  = out + (size_t)21760 * 1024;   // mem_v region (hosts query_bf first)

    // ---- workspace layout (floats) ----
    float* w      = (float*)d_ws;
    u16*   kc_bf  = (u16*)w;                     // [0, 5,242,880)
    u16*   vcT_bf = (u16*)(w + 5242880);         // [5,242,880, 10,485,760)
    float* sk     = w + 10485760;                // 327,680
    float* sv     = w + 10813440;                // 327,680
    float* svT    = w + 11141120;                // 327,680
    u16*   sk_bf  = (u16*)(w + 11468800);        // 163,840 f-equiv
    u16*   svT_bf = (u16*)(w + 11632640);        // 163,840 f-equiv
    float* alph   = w + 11796480;                // 21,760
    float* logits = w + 11859200;                // 13,926,400 (ends 25,785,600)
    // tail region (alpha-path statics), after logits:
    float* tail0  = w + 25785600;
    u16*   aW1topT = (u16*)tail0;                // 65,536 f each
    u16*   aW1midT = (u16*)(tail0 + 65536);
    u16*   aW1botT = (u16*)(tail0 + 131072);
    float* ceW    = tail0 + 196608;              // 22*128
    float* seW    = tail0 + 199424;              // 10*128
    float* cb     = tail0 + 200704;              // 128
    u16*   h_bf   = (u16*)(tail0 + 200832);      // 1,392,640 f (ends w+27,379,072)
    u16*   catB_bf = (u16*)(w + 27379072);       // 1,310,720 f (ends 28,689,792)
    u16*   sm_bf  = (u16*)(w + 28689792);        // 163,840 f  (ends 28,853,632)
    u16*   ce_bf  = (u16*)(w + 28853632);        // 11,264 f
    u16*   se_bf  = (u16*)(w + 28864896);        // 5,120 f
    if (ws_size < (size_t)29881600 * 4) return;
    if (out_size < 2 * 21760 * 1024 + 2) return;

    // --- overlays (lifetime-disjoint with their hosts) ---
    u16*   x_bf   = (u16*)logits;                // dead before gemm_logits
    float* bufA   = logits + 5570560;            // catBK  2,621,440
    float* bufB   = bufA + 2621440;              // catBV  2,621,440
    float* catBVT = bufB + 2621440;              // 2,621,440
    u16*   WqT    = (u16*)w;                     // dead before build_kc2
    u16*   WkT    = WqT + 1048576;
    u16*   WvT    = WkT + 1048576;
    u16*   kW1T   = (u16*)sv;                    // written after sv consumed
    u16*   vW1T   = kW1T + 65536;                // contiguous => [128][1024]
    u16*   kW2T   = vW1T + 65536;
    u16*   vW2T   = kW2T + 65536;
    u16*   bufAB_bf = (u16*)w;                   // [21760][128] bf16, <= kc region
    u16*   mem_bf = (u16*)memb;                  // bf16 mem in d_out first half
    u16*   query_bf = (u16*)outv;                // dead before final mem_v gemm

    const dim3 blk256(256);
    const dim3 blk512(512);

    // 0. casts / weight transposes (tcast grid = (Cc/32, R/32))
    castbf<<<dim3(2048), blk256, 0, stream>>>(x, x_bf, 21760 * 1024 / 4);
    castbf<<<dim3(320), blk256, 0, stream>>>(sm, sm_bf, 320 * 1024 / 4);
    castbf<<<dim3(2048), blk256, 0, stream>>>(cat_B, catB_bf, 2560 * 1024 / 4);
    castbf<<<dim3(22), blk256, 0, stream>>>(cat_emb, ce_bf, 22 * 1024 / 4);
    castbf<<<dim3(10), blk256, 0, stream>>>(scale_emb, se_bf, 10 * 1024 / 4);
    tcast<<<dim3(32, 32), blk256, 0, stream>>>(Wq, WqT, 1024, 1024);
    tcast<<<dim3(32, 32), blk256, 0, stream>>>(Wk, WkT, 1024, 1024);
    tcast<<<dim3(32, 32), blk256, 0, stream>>>(Wv, WvT, 1024, 1024);
    tcast<<<dim3(4, 32), blk256, 0, stream>>>(aW1,              aW1topT, 1024, 128);
    tcast<<<dim3(4, 32), blk256, 0, stream>>>(aW1 + 1024 * 128, aW1midT, 1024, 128);
    tcast<<<dim3(4, 32), blk256, 0, stream>>>(aW1 + 2048 * 128, aW1botT, 1024, 128);

    // 1. projections; big = 256-tile depth-3, small = 128-tile depth-3
    gemm256d<1><<<dim3(4, 85), blk512, 0, stream>>>(x_bf,    WqT, (float*)query_bf, 21760, 1024, 1024, 1024, nullptr, nullptr);
    gemm128d<0><<<dim3(8, 3),  blk256, 0, stream>>>(sm_bf,   WkT, sk,   320,  1024, 1024, 1024, nullptr, nullptr);
    gemm128d<0><<<dim3(8, 3),  blk256, 0, stream>>>(sm_bf,   WvT, sv,   320,  1024, 1024, 1024, nullptr, nullptr);
    gemm128d<0><<<dim3(8, 20), blk256, 0, stream>>>(catB_bf, WkT, bufA, 2560, 1024, 1024, 1024, nullptr, nullptr);
    gemm128d<0><<<dim3(8, 20), blk256, 0, stream>>>(catB_bf, WvT, bufB, 2560, 1024, 1024, 1024, nullptr, nullptr);

    // 1b. alpha-path statics (tiny)
    gemm128d<0><<<dim3(1, 1), blk256, 0, stream>>>(ce_bf, aW1midT, ceW, 22, 128, 1024, 1024, nullptr, nullptr);
    gemm128d<0><<<dim3(1, 1), blk256, 0, stream>>>(se_bf, aW1botT, seW, 10, 128, 1024, 1024, ab1, nullptr);

    // 2. derived key/value layouts
    castbf<<<dim3(320), blk256, 0, stream>>>(sk, sk_bf, 320 * 1024 / 4);
    transpose32<<<dim3(32, 10), blk256, 0, stream>>>(sv, svT, 320, 1024);
    tcast<<<dim3(32, 10), blk256, 0, stream>>>(sv, svT_bf, 320, 1024);
    transpose32<<<dim3(32, 80), blk256, 0, stream>>>(bufB, catBVT, 2560, 1024);
    // small head-weight transposes AFTER sv is consumed (they overlay sv)
    tcast<<<dim3(2, 32), blk256, 0, stream>>>(kW1, kW1T, 1024, 64);
    tcast<<<dim3(2, 32), blk256, 0, stream>>>(vW1, vW1T, 1024, 64);
    tcast<<<dim3(32, 2), blk256, 0, stream>>>(kW2, kW2T, 64, 1024);
    tcast<<<dim3(32, 2), blk256, 0, stream>>>(vW2, vW2T, 64, 1024);
    concat_bias<<<dim3(1), dim3(128), 0, stream>>>(kb1, vb1, cb);

    // 3. fused per-batch low-rank K/V builders (catB rows staged once)
    build_kc2<<<dim3(320), blk256, 0, stream>>>(sk, bufA, cat_A, cat_ids, kc_bf);
    build_vcT2<<<dim3(1024), dim3(320), 0, stream>>>(svT, catBVT, cat_A, cat_ids, vcT_bf);

    // 4. alpha gate (MFMA hidden + tiny reduce)
    gemm_halpha<<<dim3(170), blk256, 0, stream>>>(query_bf, aW1topT, ceW, seW, cat_ids, h_bf);
    alpha_reduce<<<dim3(5440), blk256, 0, stream>>>(h_bf, aW2, ab2, cat_ids, alph);

    // 5. attention as MFMA GEMMs: logits -> masked softmax (P in-place) -> PV
    gemm_logits<<<dim3(3, 3, NB), blk512, 0, stream>>>(query_bf, sk_bf, kc_bf, logits);
    softmax_kernel<<<dim3(170, NB), blk256, 0, stream>>>(logits, alph, log_temp);
    gemm_pv<<<dim3(4, 3, NB), blk512, 0, stream>>>((const u16*)logits, svT_bf, vcT_bf, mem_bf);

    // 6. final low-rank projections: fused bf16 stage-1 (N=128), two stage-2
    gemm128d<1><<<dim3(1, 170), blk256, 0, stream>>>(mem_bf, kW1T, (float*)bufAB_bf, 21760, 128, 1024, 1024, cb, nullptr);
    gemm256d<0><<<dim3(4, 85), blk512, 0, stream>>>(bufAB_bf,      kW2T, memb, 21760, 1024, 64, 128, kb2, gk);
    gemm256d<0><<<dim3(4, 85), blk512, 0, stream>>>(bufAB_bf + 64, vW2T, outv, 21760, 1024, 64, 128, vb2, gv);

    tail_zero<<<1, 64, 0, stream>>>(out + (size_t)2 * 21760 * 1024);
}